// Round 2
// baseline (1803.973 us; speedup 1.0000x reference)
//
#include <hip/hip_runtime.h>
#include <hip/hip_bf16.h>
#include <stdint.h>

// ---------------------------------------------------------------------------
// Net_75282186764473: forward == 'experiment' dynamics (stop_gradient identity).
//   per step: sq = sin(1.1*q);  p += M'^T-col dot sq (M' = dt*(c2q(W)+Qn-I),
//   augmented with a dt*e row driven by a constant ones-row in sq);
//   q += dt*p_old.
// Layout: lane = batch (64/block), wave owns 26 node-columns; M slice comes
// in via wave-uniform scalar loads (bf16-packed, unpacked with shifts); sin
// values cross waves through LDS with ONE ds_read_b32 per K-iteration.
// ---------------------------------------------------------------------------

#define NTH 512
#define WPB 8            // waves per block
#define JW 26            // node columns per wave (8*26 = 208 >= 206+pad)
#define BT 64            // batch rows per block (= lanes of each wave)
#define RK 208           // allocated slice rows (K_max = 207)
#define ROWDW 16         // dwords per slice row (32 bf16 slots, 13 used)
#define SQROWS 210       // LDS sin rows (prefetch overshoot safe)
#define LSTR 64          // floats per LDS sin row (one per batch lane)

#define SLICE_HALFS ((size_t)WPB * RK * 32)   // uint16 elems per stage slice

// Build bf16-packed, dt-scaled, column-sliced M' for one stage.
// out[(w*RK + k)*32 + jj] = bf16( dt * ( k<N : c2q(C)[k][j]+Qn[k][j]-I
//                                        k==N: e[j]  ; else 0 ) ), j=26w+jj
__global__ void prep_slices(const float* __restrict__ C,
                            const float* __restrict__ Qn,
                            const float* __restrict__ e,
                            int N, uint16_t* __restrict__ out) {
    const int j = blockIdx.x;            // 0..207
    const int t = threadIdx.x;           // 64 threads (one wave)
    const int w = j / JW, jj = j % JW;
    float s = 0.f;
    if (j < N) {
        for (int i = t; i < N; i += 64)
            s += 0.5f * (C[i * N + j] + C[j * N + i]);
        #pragma unroll
        for (int off = 32; off > 0; off >>= 1)
            s += __shfl_xor(s, off, 64);
    }
    for (int k = t; k < RK; k += 64) {
        float v = 0.f;
        if (j < N) {
            if (k < N) {
                v = (k == j) ? (-s - 1.0f)
                             : 0.5f * (C[k * N + j] + C[j * N + k]);
                v += Qn[k * N + j];
            } else if (k == N) {
                v = e[j];
            }
            v *= 0.1f;                   // fold dt
        }
        __hip_bfloat16 h = __float2bfloat16(v);
        out[(size_t)(w * RK + k) * 32 + jj] = *reinterpret_cast<uint16_t*>(&h);
    }
}

template <int N>
__device__ __forceinline__ void stage_run(float (&q)[JW], float (&p)[JW],
                                          const uint32_t* __restrict__ sliceW,
                                          float* __restrict__ sqL,
                                          int l, int w) {
    const int K = N + 1;                 // N sin rows + 1 ones-row (e drive)
    for (int s = 0; s < 5; ++s) {
        // sin phase (writes rows this wave owns) + q-update with OLD p
        #pragma unroll
        for (int jj = 0; jj < JW; ++jj) {
            const int r = w * JW + jj;
            float v;
            if (r < N)       v = __sinf(1.1f * q[jj]);
            else if (r == N) v = 1.0f;
            else             v = 0.0f;
            sqL[r * LSTR + l] = v;
            q[jj] = fmaf(0.1f, p[jj], q[jj]);
        }
        __syncthreads();
        // GEMM phase: p[jj] += sum_i sq[i][lane] * M'[i][26w+jj]
        uint32_t d[13];
        #pragma unroll
        for (int t = 0; t < 13; ++t) d[t] = sliceW[t];       // row 0 (uniform)
        float s0 = sqL[0 * LSTR + l];
        float s1 = sqL[1 * LSTR + l];
        #pragma unroll 2
        for (int i = 0; i < K; ++i) {
            const uint32_t* nr = sliceW + (size_t)(i + 1) * ROWDW;
            uint32_t dn[13];
            #pragma unroll
            for (int t = 0; t < 13; ++t) dn[t] = nr[t];      // prefetch row i+1
            float s2 = sqL[(i + 2) * LSTR + l];              // prefetch sin i+2
            #pragma unroll
            for (int t = 0; t < 13; ++t) {
                const float me = __uint_as_float(d[t] << 16);          // even j
                const float mo = __uint_as_float(d[t] & 0xFFFF0000u);  // odd j
                p[2 * t]     = fmaf(s0, me, p[2 * t]);
                p[2 * t + 1] = fmaf(s0, mo, p[2 * t + 1]);
            }
            #pragma unroll
            for (int t = 0; t < 13; ++t) d[t] = dn[t];
            s0 = s1; s1 = s2;
        }
        __syncthreads();
    }
}

__global__ __launch_bounds__(NTH, 4) void pat_main(
    const float* __restrict__ x,
    const uint32_t* __restrict__ slices,   // [2][WPB][RK][ROWDW] packed bf16
    const float* __restrict__ fac,
    float* __restrict__ out) {
    __shared__ float sqL[SQROWS * LSTR];   // 53,760 B -> 2 blocks/CU
    const int tid = threadIdx.x;
    const int l = tid & 63;                                   // batch lane
    const int w = __builtin_amdgcn_readfirstlane(tid >> 6);   // wave id (SGPR)
    const long b = (long)blockIdx.x * BT + l;

    float q[JW], p[JW];
    #pragma unroll
    for (int jj = 0; jj < JW; ++jj) {
        const int j = w * JW + jj;
        q[jj] = (j < 196) ? x[b * 196 + j] : 0.0f;
        p[jj] = 0.0f;
    }

    const uint32_t* s1b = slices + (size_t)w * RK * ROWDW;
    const uint32_t* s2b = s1b + (size_t)WPB * RK * ROWDW;

    stage_run<196>(q, p, s1b, sqL, l, w);

    // transition: q carries over (class nodes are exactly 0), p resets
    #pragma unroll
    for (int jj = 0; jj < JW; ++jj) p[jj] = 0.0f;

    stage_run<206>(q, p, s2b, sqL, l, w);

    if (w == WPB - 1) {                    // wave 7 owns nodes 182..207
        const float f = fac[0];
        #pragma unroll
        for (int jj = 0; jj < JW; ++jj) {
            const int j = w * JW + jj;
            if (j >= 196 && j < 206)
                out[b * 10 + (j - 196)] = f * q[jj];
        }
    }
}

extern "C" void kernel_launch(void* const* d_in, const int* in_sizes, int n_in,
                              void* d_out, int out_size, void* d_ws, size_t ws_size,
                              hipStream_t stream) {
    const float* x   = (const float*)d_in[0];
    const float* w1  = (const float*)d_in[1];
    const float* b1  = (const float*)d_in[2];
    const float* w2  = (const float*)d_in[3];
    const float* b2  = (const float*)d_in[4];
    const float* fac = (const float*)d_in[5];
    const float* qn1 = (const float*)d_in[6];
    const float* qn2 = (const float*)d_in[7];
    float* out = (float*)d_out;

    uint16_t* sl = (uint16_t*)d_ws;        // 2 stages x 106,496 B = 213 KB

    prep_slices<<<208, 64, 0, stream>>>(w1, qn1, b1, 196, sl);
    prep_slices<<<208, 64, 0, stream>>>(w2, qn2, b2, 206, sl + SLICE_HALFS);

    const int B = in_sizes[0] / 196;       // 65536
    pat_main<<<B / BT, NTH, 0, stream>>>(x, (const uint32_t*)d_ws, fac, out);
}

// Round 3
// 194.884 us; speedup vs baseline: 9.2566x; 9.2566x over previous
//
#include <hip/hip_runtime.h>
#include <hip/hip_bf16.h>
#include <stdint.h>

// ---------------------------------------------------------------------------
// Net_75282186764473 — forward == 'experiment' dynamics (stop_grad identity).
// Per step: sq = sin(1.1 q); q += dt*p_old; p += sq @ M' + dt*e
//   with M' = dt*(c2q(W) + Qn - I), all in bf16 MFMA 16x16x32.
// Layout: batch m in MFMA C/D rows, node n in C/D cols. M' pre-packed into
// B-fragments (registers, wave w owns n-tiles {w, w+8}); sin crosses waves
// via a bf16 LDS tile (written in C/D layout, read as dense A-frag b128).
// Stage1: N=196 (cols/rows >=196 are zero in M1' -> class nodes stay 0).
// Stage2: N=206. Output = fac * q[:,196:206].
// ---------------------------------------------------------------------------

typedef __attribute__((ext_vector_type(8))) short bh8;
typedef __attribute__((ext_vector_type(4))) float f32x4;

#define TILES 13        // n-tiles of 16 -> 208 cols (>=206)
#define KSTEPS 7        // k-steps of 32 -> 224 (>=208, rows 208..223 zeroed)
#define KSTR 232        // bf16 per LDS sin row (464 B: 16B-aligned, 2-way banks)
#define MB 32           // batch rows per block (2 m-tiles)

static __device__ __forceinline__ uint16_t bf16_bits(float v) {
    __hip_bfloat16 h = __float2bfloat16(v);
    return *reinterpret_cast<uint16_t*>(&h);
}

// d[col] = -sum_i 0.5*(C[i][j]+C[j][i])  (the c2q diagonal), both stages.
__global__ void prep_diag(const float* __restrict__ C1, const float* __restrict__ C2,
                          float* __restrict__ d) {
    const int bid = blockIdx.x;            // 0..401
    const int t = threadIdx.x;             // 64
    const float* C = (bid < 196) ? C1 : C2;
    const int N = (bid < 196) ? 196 : 206;
    const int j = (bid < 196) ? bid : bid - 196;
    float s = 0.f;
    for (int i = t; i < N; i += 64) s += 0.5f * (C[i * N + j] + C[j * N + i]);
    #pragma unroll
    for (int off = 32; off > 0; off >>= 1) s += __shfl_xor(s, off, 64);
    if (t == 0) d[bid] = -s;
}

// Pack M' = dt*(c2q(C)+Qn-I) directly into MFMA B-fragment order:
// frag[((stage*13+tile)*7+ks)*64 + lane] = 8 bf16, elem j = M'[k][n],
//   k = ks*32 + quad*8 + j,  n = tile*16 + (lane&15).
__global__ void pack_frags(const float* __restrict__ C1, const float* __restrict__ Qn1,
                           const float* __restrict__ C2, const float* __restrict__ Qn2,
                           const float* __restrict__ dbuf, uint16_t* __restrict__ frag) {
    const int bid = blockIdx.x;            // 0..25
    const int st = bid / TILES, tile = bid % TILES;
    const float* C  = st ? C2 : C1;
    const float* Qn = st ? Qn2 : Qn1;
    const float* d  = dbuf + (st ? 196 : 0);
    const int N = st ? 206 : 196;
    const int lane = threadIdx.x & 63;
    const int grp  = threadIdx.x >> 6;     // 0..3
    const int quad = (lane >> 4) & 3;
    const int n = tile * 16 + (lane & 15);
    for (int ks = grp; ks < KSTEPS; ks += 4) {
        uint16_t vals[8];
        #pragma unroll
        for (int j = 0; j < 8; ++j) {
            const int k = ks * 32 + quad * 8 + j;
            float v = 0.f;
            if (k < N && n < N) {
                if (k == n) v = d[n] + Qn[n * N + n] - 1.0f;
                else        v = 0.5f * (C[k * N + n] + C[n * N + k]) + Qn[k * N + n];
                v *= 0.1f;                 // fold dt
            }
            vals[j] = bf16_bits(v);
        }
        const size_t off = ((size_t)(st * TILES + tile) * KSTEPS + ks) * 64 + lane;
        reinterpret_cast<uint4*>(frag)[off] = *reinterpret_cast<uint4*>(vals);
    }
}

__global__ __launch_bounds__(512, 4) void pat_main(
    const float* __restrict__ x, const uint16_t* __restrict__ frag,
    const float* __restrict__ e1, const float* __restrict__ e2,
    const float* __restrict__ fac, float* __restrict__ out) {
    __shared__ __align__(16) uint16_t sinb[MB * KSTR];    // 14,848 B
    const int tid = threadIdx.x;
    const int lane = tid & 63;
    const int w = __builtin_amdgcn_readfirstlane(tid >> 6);   // wave id
    const int c = lane & 15;
    const int quad = lane >> 4;
    const long b0 = (long)blockIdx.x * MB;

    const int t0 = w, t1 = w + 8;
    const bool has1 = (t1 < TILES);        // waves 0..4 own a second tile

    // zero K-pad columns 208..223 (written once; never touched again)
    sinb[(tid >> 4) * KSTR + 208 + (tid & 15)] = 0;

    // ---- state in C/D layout: q[mt][tt][r], p as MFMA accumulator ----
    float q[2][2][4];
    f32x4 p[2][2];
    #pragma unroll
    for (int mt = 0; mt < 2; ++mt)
        #pragma unroll
        for (int tt = 0; tt < 2; ++tt) {
            const int tile = tt ? t1 : t0;
            const int n = tile * 16 + c;
            #pragma unroll
            for (int r = 0; r < 4; ++r) {
                const long m = b0 + mt * 16 + quad * 4 + r;
                q[mt][tt][r] = (tt == 1 && !has1) ? 0.f
                             : ((n < 196) ? x[m * 196 + n] : 0.f);
                p[mt][tt][r] = 0.f;
            }
        }

    // ---- M' B-fragments in registers (reloaded at stage switch) ----
    bh8 B[2][KSTEPS];
    float ereg[2];
    const bh8* fragv = reinterpret_cast<const bh8*>(frag);
    #pragma unroll
    for (int tt = 0; tt < 2; ++tt) {
        const int tile = tt ? t1 : t0;
        if (tile < TILES)
            #pragma unroll
            for (int ks = 0; ks < KSTEPS; ++ks)
                B[tt][ks] = fragv[((size_t)tile * KSTEPS + ks) * 64 + lane];
        const int n = tile * 16 + c;
        ereg[tt] = (n < 196) ? 0.1f * e1[n] : 0.f;
    }
    const float f = fac[0];

    for (int st = 0; st < 10; ++st) {
        if (st == 5) {                     // stage transition
            #pragma unroll
            for (int tt = 0; tt < 2; ++tt) {
                const int tile = tt ? t1 : t0;
                if (tile < TILES)
                    #pragma unroll
                    for (int ks = 0; ks < KSTEPS; ++ks)
                        B[tt][ks] = fragv[((size_t)(TILES + tile) * KSTEPS + ks) * 64 + lane];
                const int n = tile * 16 + c;
                ereg[tt] = (n < 206) ? 0.1f * e2[n] : 0.f;
                p[0][tt] = 0.f; p[1][tt] = 0.f;       // p resets, q carries
            }
        }
        // sin(q_old) -> LDS (bf16, [m][k] row-major); then q += dt*p_old
        #pragma unroll
        for (int mt = 0; mt < 2; ++mt)
            #pragma unroll
            for (int tt = 0; tt < 2; ++tt) {
                if (tt == 1 && !has1) continue;
                const int tile = tt ? t1 : t0;
                #pragma unroll
                for (int r = 0; r < 4; ++r) {
                    const float sv = __sinf(1.1f * q[mt][tt][r]);
                    sinb[(mt * 16 + quad * 4 + r) * KSTR + tile * 16 + c] = bf16_bits(sv);
                    q[mt][tt][r] += 0.1f * p[mt][tt][r];
                }
            }
        __syncthreads();
        // p += sin @ M'  (dense A-frag b128 reads; B from registers)
        #pragma unroll
        for (int ks = 0; ks < KSTEPS; ++ks) {
            const bh8 a0 = *reinterpret_cast<const bh8*>(&sinb[c * KSTR + ks * 32 + quad * 8]);
            const bh8 a1 = *reinterpret_cast<const bh8*>(&sinb[(16 + c) * KSTR + ks * 32 + quad * 8]);
            p[0][0] = __builtin_amdgcn_mfma_f32_16x16x32_bf16(a0, B[0][ks], p[0][0], 0, 0, 0);
            p[1][0] = __builtin_amdgcn_mfma_f32_16x16x32_bf16(a1, B[0][ks], p[1][0], 0, 0, 0);
            if (has1) {
                p[0][1] = __builtin_amdgcn_mfma_f32_16x16x32_bf16(a0, B[1][ks], p[0][1], 0, 0, 0);
                p[1][1] = __builtin_amdgcn_mfma_f32_16x16x32_bf16(a1, B[1][ks], p[1][1], 0, 0, 0);
            }
        }
        // e-drive: p += dt*e
        #pragma unroll
        for (int mt = 0; mt < 2; ++mt)
            #pragma unroll
            for (int tt = 0; tt < 2; ++tt)
                #pragma unroll
                for (int r = 0; r < 4; ++r)
                    p[mt][tt][r] += ereg[tt];
        __syncthreads();
    }

    // output: nodes 196..205 live in tile 12 = wave 4's t1
    if (w == 4) {
        const int n = 192 + c;
        if (n >= 196 && n < 206) {
            #pragma unroll
            for (int mt = 0; mt < 2; ++mt)
                #pragma unroll
                for (int r = 0; r < 4; ++r)
                    out[(b0 + mt * 16 + quad * 4 + r) * 10 + (n - 196)] = f * q[mt][1][r];
        }
    }
}

extern "C" void kernel_launch(void* const* d_in, const int* in_sizes, int n_in,
                              void* d_out, int out_size, void* d_ws, size_t ws_size,
                              hipStream_t stream) {
    const float* x   = (const float*)d_in[0];
    const float* w1  = (const float*)d_in[1];
    const float* b1  = (const float*)d_in[2];
    const float* w2  = (const float*)d_in[3];
    const float* b2  = (const float*)d_in[4];
    const float* fac = (const float*)d_in[5];
    const float* qn1 = (const float*)d_in[6];
    const float* qn2 = (const float*)d_in[7];
    float* out = (float*)d_out;

    float*    diag = (float*)d_ws;                       // 402 f32
    uint16_t* frg  = (uint16_t*)((float*)d_ws + 512);    // 2*13*7*64*8 bf16 = 182 KB

    prep_diag<<<402, 64, 0, stream>>>(w1, w2, diag);
    pack_frags<<<26, 256, 0, stream>>>(w1, qn1, w2, qn2, diag, frg);

    const int B = in_sizes[0] / 196;                     // 65536
    pat_main<<<B / MB, 512, 0, stream>>>(x, frg, b1, b2, fac, out);
}